// Round 1
// baseline (397.794 us; speedup 1.0000x reference)
//
#include <hip/hip_runtime.h>

// CostTokenizer: 3 pyramid levels, local correlation (R=3 -> 49 offsets, circular
// wrap per jnp.roll) + 1x1 conv (49 -> 192) + bias. All fp32.
//
// Layout facts:
//  l: [T=3, B=2, C, H, W]; pairs (t, t+1) for t in {0,1}, b in {0,1} -> 4 pairs.
//  corr[k] = sum_c f1[c,h,w] * f2[c, (h-dy)%H, (w-dx)%W], k = (dy+3)*7 + (dx+3)
//  tok[t,b,d,h,w] = b[d] + (1/sqrt(C)) * sum_k corr[k] * w[k,d]
//  out = concat(tok1 flat, tok2 flat, tok3 flat)

#define TD 192

template<int C, int H, int W>
__device__ __forceinline__ void level_tile(
    const float* __restrict__ lvl, const float* __restrict__ wm,
    const float* __restrict__ bias, float* __restrict__ out,
    int pair, int tY, int tX, float scale, float4* hs)
{
    const int HW = H * W;
    const int t  = pair >> 1, bb = pair & 1;
    const float* f1 = lvl + (t * 2 + bb) * C * HW;
    const float* f2 = lvl + ((t + 1) * 2 + bb) * C * HW;

    const int tid = threadIdx.x;
    const int tx  = tid & 15, ty = tid >> 4;
    const int x0  = tX * 16, y0 = tY * 16;
    const int x   = x0 + tx, y = y0 + ty;

    float acc[49];
#pragma unroll
    for (int k = 0; k < 49; ++k) acc[k] = 0.f;

    // channel chunks of 4, f2 halo staged in LDS as float4(4 channels)
    for (int cg = 0; cg < C / 4; ++cg) {
        __syncthreads();  // protect previous chunk's LDS reads
        const float* f2c = f2 + cg * 4 * HW;
        for (int p = tid; p < 22 * 22; p += 256) {
            int r = p / 22, c = p - r * 22;
            int gy = y0 - 3 + r; if (gy < 0) gy += H; if (gy >= H) gy -= H;
            int gx = x0 - 3 + c; if (gx < 0) gx += W; if (gx >= W) gx -= W;
            const float* s = f2c + gy * W + gx;
            float4 v; v.x = s[0]; v.y = s[HW]; v.z = s[2 * HW]; v.w = s[3 * HW];
            hs[r * 23 + c] = v;  // stride 23 float4s: breaks pow2 banking
        }
        const float* f1c = f1 + cg * 4 * HW + y * W + x;
        float a0 = f1c[0], a1 = f1c[HW], a2 = f1c[2 * HW], a3 = f1c[3 * HW];
        __syncthreads();

        // need f2[y - dy] with dy = a-3  ->  halo row = ty + 6 - a (halo origin y0-3)
#pragma unroll
        for (int a = 0; a < 7; ++a) {
#pragma unroll
            for (int b = 0; b < 7; ++b) {
                float4 v = hs[(ty + 6 - a) * 23 + (tx + 6 - b)];
                float s = acc[a * 7 + b];
                s = fmaf(a0, v.x, s);
                s = fmaf(a1, v.y, s);
                s = fmaf(a2, v.z, s);
                s = fmaf(a3, v.w, s);
                acc[a * 7 + b] = s;
            }
        }
    }

#pragma unroll
    for (int k = 0; k < 49; ++k) acc[k] *= scale;

    // 49 -> 192 contraction; w/bias uniform -> scalar loads; 4 indep FMA chains
    float* op = out + (pair * TD) * HW + y * W + x;
    for (int d = 0; d < TD; d += 4) {
        float s0 = bias[d + 0], s1 = bias[d + 1], s2 = bias[d + 2], s3 = bias[d + 3];
        const float* wp = wm + d;
#pragma unroll
        for (int k = 0; k < 49; ++k) {
            float a = acc[k];
            s0 = fmaf(wp[k * TD + 0], a, s0);
            s1 = fmaf(wp[k * TD + 1], a, s1);
            s2 = fmaf(wp[k * TD + 2], a, s2);
            s3 = fmaf(wp[k * TD + 3], a, s3);
        }
        op[(d + 0) * HW] = s0;
        op[(d + 1) * HW] = s1;
        op[(d + 2) * HW] = s2;
        op[(d + 3) * HW] = s3;
    }
}

__global__ __launch_bounds__(256)
void cost_tokenizer(const float* __restrict__ l1, const float* __restrict__ l2,
                    const float* __restrict__ l3,
                    const float* __restrict__ w1, const float* __restrict__ b1,
                    const float* __restrict__ w2, const float* __restrict__ b2,
                    const float* __restrict__ w3, const float* __restrict__ b3,
                    float* __restrict__ out)
{
    __shared__ float4 hs[22 * 23];  // 8.1 KB halo buffer (tile-size only, level-agnostic)
    int bid = blockIdx.x;
    // heaviest blocks first (L3 has C=192, most channel chunks), L1 bulk last
    if (bid < 16) {
        int r = bid;                       // L3: 4 pairs x 2x2 tiles of 16
        level_tile<192, 32, 32>(l3, w3, b3, out + 15728640,
                                r >> 2, (r >> 1) & 1, r & 1,
                                0.072168783648703216f, hs);
    } else if (bid < 80) {
        int r = bid - 16;                  // L2: 4 pairs x 4x4 tiles
        level_tile<128, 64, 64>(l2, w2, b2, out + 12582912,
                                r >> 4, (r >> 2) & 3, r & 3,
                                0.088388347648318447f, hs);
    } else {
        int r = bid - 80;                  // L1: 4 pairs x 8x8 tiles
        level_tile<64, 128, 128>(l1, w1, b1, out,
                                 r >> 6, (r >> 3) & 7, r & 7,
                                 0.125f, hs);
    }
}

extern "C" void kernel_launch(void* const* d_in, const int* in_sizes, int n_in,
                              void* d_out, int out_size, void* d_ws, size_t ws_size,
                              hipStream_t stream)
{
    const float* l1 = (const float*)d_in[0];
    const float* l2 = (const float*)d_in[1];
    const float* l3 = (const float*)d_in[2];
    const float* w1 = (const float*)d_in[3];
    const float* b1 = (const float*)d_in[4];
    const float* w2 = (const float*)d_in[5];
    const float* b2 = (const float*)d_in[6];
    const float* w3 = (const float*)d_in[7];
    const float* b3 = (const float*)d_in[8];
    float* out = (float*)d_out;

    hipLaunchKernelGGL(cost_tokenizer, dim3(336), dim3(256), 0, stream,
                       l1, l2, l3, w1, b1, w2, b2, w3, b3, out);
}